// Round 7
// baseline (284.122 us; speedup 1.0000x reference)
//
#include <hip/hip_runtime.h>

#define NUM_K   4096
#define CDIM    64
#define HWDIM   4096            // 64*64
#define NVEC    65536           // 16 * 64 * 64
#define CHW     (CDIM * HWDIM)  // 262144
#define KT      32              // codes per k-tile (16 per wave)
#define NKT_SL  64              // k-tiles per slice (2048 codes)
// rescue margin on biased s/2 scale: bf16-split budget 2e-3 (validated r4-r6)
// + 7-bit mask granularity q<=3.9e-3 (scores < 512) + slack
#define TAUH    6e-3f
#define SBIAS   128.0f          // score bias: s' = 128 + (wsq - 2 x.w)/2 > 0 always
#define RB      16              // rescue batch width (vectors per codebook pass)

// ---- output layout (floats, concatenated in reference return order) ----
#define O_Q     0               // quantized_ste  [16,64,64,64] = 4194304
#define O_LOSS  4194304         // scalar
#define O_IDX   4194305         // encoding_indices [16,64,64] = 65536 (as float)
#define O_W     4259841         // new_weight   [4096,64] = 262144
#define O_CS    4521985         // new_cluster_size [4096]
#define O_EW    4526081         // new_ema_w    [4096,64] = 262144

// ---- workspace layout (floats) ----
#define W_WSQ    0               // wsq/2 + SBIAS [4096]
#define W_BIDX   4096            // best idx int[65536]
#define W_CNT    69632           // counts[4096] + loss + esum + rcnt (zeroed by prep)
#define W_LOSS   73728
#define W_ESUM   73729           // sum(ema_cluster_size)
#define W_RCNT   73730
#define W_DW     73732           // dw [262144] (zeroed by prep; no overlays)
// high-water: 335876 floats = 1.34 MB
// keys[4][65536] u64 + b2s[4][65536] f32 live in the dead O_Q output scratch:
// wh/wl [0,262144) ; rlist [262144,327680) ; keys [327680,851968) ;
// b2s [851968,1114112) -- all overwritten by assign's O_Q writes afterwards.

typedef unsigned long long u64;
typedef __bf16 bf16x8 __attribute__((ext_vector_type(8)));
typedef float  f32x4  __attribute__((ext_vector_type(4)));

__device__ __forceinline__ unsigned f2ord(float f) {
    unsigned u = __float_as_uint(f);
    return (u & 0x80000000u) ? ~u : (u | 0x80000000u);
}
__device__ __forceinline__ unsigned umn(unsigned a, unsigned b) { return a < b ? a : b; }
__device__ __forceinline__ unsigned umx(unsigned a, unsigned b) { return a > b ? a : b; }
__device__ __forceinline__ u64 umn64(u64 a, u64 b) { return a < b ? a : b; }

// Per codebook row: biased wsq/2 + SBIAS (fp32) + bf16 hi/lo split copies.
// Also zeroes counts/loss/esum/rcnt AND dw (grid is exactly CHW threads).
__global__ void __launch_bounds__(256)
prep_kernel(const float* __restrict__ w, float* __restrict__ wsqh,
            __bf16* __restrict__ wh, __bf16* __restrict__ wl,
            float* __restrict__ zero_area, float* __restrict__ dw) {
    int gid = blockIdx.x * 256 + threadIdx.x;
    dw[gid] = 0.f;                             // gid in [0, CHW)
    if (gid < 4099) zero_area[gid] = 0.f;      // counts[4096]+loss+esum+rcnt
    int wv = threadIdx.x >> 6, lane = threadIdx.x & 63;
    int row = blockIdx.x * 4 + wv;
    float v = w[row * CDIM + lane];
    __bf16 h = (__bf16)v;
    __bf16 l = (__bf16)(v - (float)h);         // v - hi exact in fp32
    wh[row * CDIM + lane] = h;
    wl[row * CDIM + lane] = l;
    float sq = v * v;
#pragma unroll
    for (int m = 1; m < 64; m <<= 1) sq += __shfl_xor(sq, m, 64);
    if (lane == 0) wsqh[row] = 0.5f * sq + SBIAS;
}

// Fused bf16x3-split MFMA GEMM + argmin.
// THIS ROUND: barrier-free dual-wave decomposition. Every prior schedule was
// convoy-limited: waves sharing the B tile need a per-kt __syncthreads whose
// full vmcnt/lgkm drain caps MfmaUtil at ~39%. Here each wave owns ALL 128
// rows x a PRIVATE 16-code half of each k-tile: B staging (reg->LDS ping-pong,
// the r2-proven map restricted to 16 codes) is wave-private, so after the two
// x-staging barriers the k-loop has ZERO barriers -- each wave free-runs with
// compiler-managed per-wave waitcnts. Block VMEM traffic identical to r2
// (2x4KB/kt). Waves emit keys as "virtual slices": keys[4][NVEC], merged by
// a 4-way combine. MFMA accumulation order bit-identical to r2.
__global__ void __launch_bounds__(128, 2)
argmin_mfma(const float* __restrict__ x,
            const __bf16* __restrict__ wh_g, const __bf16* __restrict__ wl_g,
            const float* __restrict__ wsqh_g,
            u64* __restrict__ keys, float* __restrict__ b2s) {
    extern __shared__ __bf16 smem[];           // 32768 B
    char* xs_h = (char*)smem;                  // [128 rows][128 B] swizzled
    char* xs_l = xs_h + 16384;
    char* bsb  = (char*)smem;                  // overlay: per-wave 2x4KB buffers

    int t = threadIdx.x, wv = t >> 6, lane = t & 63;
    int n0 = blockIdx.x * 128;
    int b = n0 >> 12, hw0 = n0 & (HWDIM - 1);
    int slice = blockIdx.y;
    int kbase = slice * (NUM_K / 2);

    // 1) stage -x hi/lo; row = t, 8 col-groups of 8 ch; b128 swizzled writes.
    {
        const float* xb = x + b * CHW + hw0 + t;
#pragma unroll
        for (int j = 0; j < 8; ++j) {
            bf16x8 hi, lo;
#pragma unroll
            for (int cc = 0; cc < 8; ++cc) {
                float v = -xb[(j * 8 + cc) * HWDIM];
                __bf16 h = (__bf16)v;
                hi[cc] = h;
                lo[cc] = (__bf16)(v - (float)h);   // exact in fp32
            }
            int bo = (t * 128 + j * 16) ^ ((t & 7) << 4);
            *(bf16x8*)(xs_h + bo) = hi;
            *(bf16x8*)(xs_l + bo) = lo;
        }
    }
    __syncthreads();

    int nn = lane & 15, q4 = lane >> 4;
    // 2) A-frags -> registers: BOTH waves take all 128 rows (8 m-slots).
    bf16x8 ah[8][2], al[8][2];
#pragma unroll
    for (int m = 0; m < 8; ++m) {
        int id = m * 16 + nn;
#pragma unroll
        for (int ch = 0; ch < 2; ++ch) {
            int bo = (id * 128 + (q4 + ch * 4) * 16) ^ ((id & 7) << 4);
            ah[m][ch] = *(const bf16x8*)(xs_h + bo);
            al[m][ch] = *(const bf16x8*)(xs_l + bo);
        }
    }
    __syncthreads();   // both waves done with xs -> LDS reusable for B buffers

    // Per-wave-private B staging (r2 map restricted to 16 codes):
    // wave buffer = bsb + wv*8192 + (kt&1)*4096. Per 4KB tile: hi units
    // [0,2048) lo units [2048,4096); unit u = chunk*16 + code at u*16B.
    // Lane l writes units {l, l+64} of each section (consecutive 16B, no
    // conflict); reads o1=(q4*16+nn)*16, o2=((q4+4)*16+nn)*16.
    char* mybuf = bsb + wv * 8192;
    long gA = (long)(kbase + wv * 16 + (lane & 15)) * 64 + (lane >> 4) * 8;
    int wl0 = (lane) * 16, wl1 = (lane + 64) * 16;  // write offsets in section

    // stage tile 0 into buffer 0
    {
        bf16x8 h0 = *(const bf16x8*)(wh_g + gA);
        bf16x8 h1 = *(const bf16x8*)(wh_g + gA + 32);
        bf16x8 l0 = *(const bf16x8*)(wl_g + gA);
        bf16x8 l1 = *(const bf16x8*)(wl_g + gA + 32);
        *(bf16x8*)(mybuf + wl0)        = h0;
        *(bf16x8*)(mybuf + wl1)        = h1;
        *(bf16x8*)(mybuf + 2048 + wl0) = l0;
        *(bf16x8*)(mybuf + 2048 + wl1) = l1;
    }

    unsigned b1k[32], b2k[32];
#pragma unroll
    for (int s = 0; s < 32; ++s) { b1k[s] = 0xFFFFFFFFu; b2k[s] = 0xFFFFFFFFu; }

    int o1 = (q4 * 16 + nn) * 16, o2 = ((q4 + 4) * 16 + nn) * 16;  // bytes

    for (int kt = 0; kt < NKT_SL; ++kt) {
        bf16x8 st0h, st1h, st0l, st1l;
        bool pre = (kt + 1 < NKT_SL);
        if (pre) {   // issue next-tile global loads early; latency spans MFMA
            long g = gA + (long)(kt + 1) * 2048;
            st0h = *(const bf16x8*)(wh_g + g);
            st1h = *(const bf16x8*)(wh_g + g + 32);
            st0l = *(const bf16x8*)(wl_g + g);
            st1l = *(const bf16x8*)(wl_g + g + 32);
        }

        char* base = mybuf + (kt & 1) * 4096;
        bf16x8 bh0 = *(const bf16x8*)(base + o1);
        bf16x8 bh1 = *(const bf16x8*)(base + o2);
        bf16x8 bl0 = *(const bf16x8*)(base + 2048 + o1);
        bf16x8 bl1 = *(const bf16x8*)(base + 2048 + o2);

        float wS = wsqh_g[kbase + kt * KT + wv * 16 + nn];  // biased, L1-hot
        unsigned tg = (unsigned)kt;

#pragma unroll
        for (int m = 0; m < 8; ++m) {
            f32x4 acc = {wS, wS, wS, wS};  // acc = SBIAS + wsq/2 - dot (> 0)
            acc = __builtin_amdgcn_mfma_f32_16x16x32_bf16(ah[m][0], bh0, acc, 0, 0, 0);
            acc = __builtin_amdgcn_mfma_f32_16x16x32_bf16(ah[m][1], bh1, acc, 0, 0, 0);
            acc = __builtin_amdgcn_mfma_f32_16x16x32_bf16(al[m][0], bh0, acc, 0, 0, 0);
            acc = __builtin_amdgcn_mfma_f32_16x16x32_bf16(al[m][1], bh1, acc, 0, 0, 0);
            acc = __builtin_amdgcn_mfma_f32_16x16x32_bf16(ah[m][0], bl0, acc, 0, 0, 0);
            acc = __builtin_amdgcn_mfma_f32_16x16x32_bf16(ah[m][1], bl1, acc, 0, 0, 0);
#pragma unroll
            for (int r = 0; r < 4; ++r) {
                unsigned ka = (__float_as_uint(acc[r]) & 0xFFFFFF80u) | tg;  // v_and_or_b32
                int s8 = m * 4 + r;
                b2k[s8] = umn(b2k[s8], umx(b1k[s8], ka));
                b1k[s8] = umn(b1k[s8], ka);
            }
        }

        if (pre) {
            char* nb = mybuf + ((kt + 1) & 1) * 4096;
            *(bf16x8*)(nb + wl0)        = st0h;
            *(bf16x8*)(nb + wl1)        = st1h;
            *(bf16x8*)(nb + 2048 + wl0) = st0l;
            *(bf16x8*)(nb + 2048 + wl1) = st1l;
        }
        // no barrier: buffers are wave-private; per-wave lgkm/vmcnt ordering
        // (compiler-inserted) is sufficient.
    }

    // unpack: tag = kt, code = (kbase + wv*16 + nn) + tag*32
    int cbase = kbase + wv * 16 + nn;
    float s1[32], sb2[32]; int code[32];
#pragma unroll
    for (int s = 0; s < 32; ++s) {
        s1[s]  = __uint_as_float(b1k[s] & 0xFFFFFF80u);
        sb2[s] = __uint_as_float(b2k[s] & 0xFFFFFF80u);
        code[s] = cbase + (int)(b1k[s] & 0x7Fu) * 32;
    }
    // cross-lane merge over the 16 code-classes (lanes sharing q4 hold the
    // same rows, different nn-codes)
#pragma unroll
    for (int msk = 1; msk < 16; msk <<= 1) {
#pragma unroll
        for (int s = 0; s < 32; ++s) {
            float os1 = __shfl_xor(s1[s], msk, 64);
            float ob2 = __shfl_xor(sb2[s], msk, 64);
            int   oc  = __shfl_xor(code[s], msk, 64);
            sb2[s] = fminf(fminf(sb2[s], ob2), fmaxf(s1[s], os1));
            if (os1 < s1[s]) code[s] = oc;   // exact ties -> margin 0 -> rescued
            s1[s] = fminf(s1[s], os1);
        }
    }
    if (nn == 0) {
        int vsl = slice * 2 + wv;            // virtual slice
#pragma unroll
        for (int s = 0; s < 32; ++s) {
            int m = s >> 2, r = s & 3;
            int v = n0 + m * 16 + q4 * 4 + r;
            keys[vsl * NVEC + v] = ((u64)__float_as_uint(s1[s]) << 32) | (unsigned)code[s];
            b2s[vsl * NVEC + v]  = sb2[s];
        }
    }
}

// Merge the 4 virtual K-slices; also reduce sum(ecs) -> esum.
__global__ void __launch_bounds__(256)
combine_kernel(const u64* __restrict__ keys, const float* __restrict__ b2s,
               const float* __restrict__ ecs, float* __restrict__ esum,
               int* __restrict__ best_idx, int* __restrict__ rcnt,
               int* __restrict__ rlist) {
    int n = blockIdx.x * 256 + threadIdx.x;
    if (n < NUM_K) {                       // blocks 0-15: ecs sum
        float v = ecs[n];
#pragma unroll
        for (int m = 1; m < 64; m <<= 1) v += __shfl_xor(v, m, 64);
        if ((threadIdx.x & 63) == 0) atomicAdd(esum, v);
    }
    u64 k0 = keys[n],            k1 = keys[NVEC + n];
    u64 k2 = keys[2 * NVEC + n], k3 = keys[3 * NVEC + n];
    u64 m01 = umn64(k0, k1), m23 = umn64(k2, k3);
    u64 km = umn64(m01, m23);              // equal score -> lowest code wins
    best_idx[n] = (int)(km & 0xFFFFFFFFu);
    float s0 = __uint_as_float((unsigned)(k0 >> 32));   // biased > 0: bits monotone
    float s1 = __uint_as_float((unsigned)(k1 >> 32));
    float s2 = __uint_as_float((unsigned)(k2 >> 32));
    float s3 = __uint_as_float((unsigned)(k3 >> 32));
    float lo01 = fminf(s0, s1), hi01 = fmaxf(s0, s1);
    float lo23 = fminf(s2, s3), hi23 = fmaxf(s2, s3);
    float lo  = fminf(lo01, lo23);
    float sec = fminf(fmaxf(lo01, lo23), fminf(hi01, hi23));  // 2nd-lowest of s0..s3
    float b2m = fminf(fminf(b2s[n], b2s[NVEC + n]),
                      fminf(b2s[2 * NVEC + n], b2s[3 * NVEC + n]));
    float m2 = fminf(b2m, sec);            // union second-best
    if (m2 - lo < TAUH) {
        int p = atomicAdd(rcnt, 1);
        rlist[p] = n;
    }
}

// Exact fp32 re-argmin for flagged (near-tie) vectors, BATCHED: 16 vectors
// share one pass over the 1 MB codebook. Same score math, same u64-key tie
// semantics (lower k wins).
#define RSTEP(C4, D0, D1)                                               \
    {                                                                   \
        int c_ = cc + (C4);                                             \
        f32x4 xv0 = *(const f32x4*)&xsT[c_][0];                         \
        f32x4 xv1 = *(const f32x4*)&xsT[c_][4];                         \
        f32x4 xv2 = *(const f32x4*)&xsT[c_][8];                         \
        f32x4 xv3 = *(const f32x4*)&xsT[c_][12];                        \
        float wa0 = a0[(C4)], wa1 = a1[(C4)];                           \
        _Pragma("unroll")                                               \
        for (int v = 0; v < 4; ++v) {                                   \
            D0[v]      = fmaf(xv0[v], wa0, D0[v]);                      \
            D0[v + 4]  = fmaf(xv1[v], wa0, D0[v + 4]);                  \
            D0[v + 8]  = fmaf(xv2[v], wa0, D0[v + 8]);                  \
            D0[v + 12] = fmaf(xv3[v], wa0, D0[v + 12]);                 \
            D1[v]      = fmaf(xv0[v], wa1, D1[v]);                      \
            D1[v + 4]  = fmaf(xv1[v], wa1, D1[v + 4]);                  \
            D1[v + 8]  = fmaf(xv2[v], wa1, D1[v + 8]);                  \
            D1[v + 12] = fmaf(xv3[v], wa1, D1[v + 12]);                 \
        }                                                               \
    }

__global__ void __launch_bounds__(256)
rescue_kernel(const float* __restrict__ x, const float* __restrict__ w,
              const float* __restrict__ wsqh, int* __restrict__ best_idx,
              const int* __restrict__ rcnt, const int* __restrict__ rlist) {
    __shared__ float xsT[64][20];      // [c][v] transposed; rows 80B (16B-mult)
    __shared__ int   nl[RB];
    __shared__ u64   wred[4][RB];

    int t = threadIdx.x;
    int cnt = *rcnt;
    int nbatch = (cnt + RB - 1) / RB;
    for (int batch = blockIdx.x; batch < nbatch; batch += gridDim.x) {
        int base = batch * RB;
        int bcnt = cnt - base; if (bcnt > RB) bcnt = RB;
        if (t < RB) nl[t] = rlist[base + (t < bcnt ? t : 0)];
        __syncthreads();
        for (int i = t; i < 64 * RB; i += 256) {   // stage transposed x batch
            int c = i >> 4, v = i & 15;
            int n = nl[v];
            xsT[c][v] = x[(n >> 12) * CHW + c * HWDIM + (n & (HWDIM - 1))];
        }
        __syncthreads();

        u64 local[RB];
#pragma unroll
        for (int v = 0; v < RB; ++v) local[v] = ~0ull;

        for (int j = 0; j < 8; ++j) {              // 16 rows/thread, in pairs
            int k0 = t + (2 * j) * 256, k1 = k0 + 256;
            const float* w0 = w + k0 * CDIM;
            const float* w1 = w + k1 * CDIM;
            float dA0[RB], dB0[RB], dA1[RB], dB1[RB];
#pragma unroll
            for (int v = 0; v < RB; ++v) { dA0[v] = dB0[v] = dA1[v] = dB1[v] = 0.f; }
            for (int cc = 0; cc < CDIM; cc += 4) {
                f32x4 a0 = *(const f32x4*)(w0 + cc);
                f32x4 a1 = *(const f32x4*)(w1 + cc);
                RSTEP(0, dA0, dA1)
                RSTEP(1, dA0, dA1)
                RSTEP(2, dB0, dB1)
                RSTEP(3, dB0, dB1)
            }
            float ws0 = wsqh[k0], ws1 = wsqh[k1];
#pragma unroll
            for (int v = 0; v < RB; ++v) {
                float s0 = ws0 - (dA0[v] + dB0[v]);
                float s1 = ws1 - (dA1[v] + dB1[v]);
                u64 key0 = ((u64)f2ord(s0) << 32) | (unsigned)k0;
                u64 key1 = ((u64)f2ord(s1) << 32) | (unsigned)k1;
                local[v] = umn64(local[v], umn64(key0, key1));
            }
        }

        // reduce: wave shuffle, then cross-wave via LDS
#pragma unroll
        for (int v = 0; v < RB; ++v) {
            u64 lv = local[v];
#pragma unroll
            for (int m = 1; m < 64; m <<= 1) {
                u64 o = __shfl_xor(lv, m, 64);
                lv = umn64(lv, o);
            }
            local[v] = lv;
        }
        if ((t & 63) == 0) {
            int wv = t >> 6;
#pragma unroll
            for (int v = 0; v < RB; ++v) wred[wv][v] = local[v];
        }
        __syncthreads();
        if (t < bcnt) {
            u64 m0 = umn64(wred[0][t], wred[1][t]);
            u64 m1 = umn64(wred[2][t], wred[3][t]);
            best_idx[nl[t]] = (int)(umn64(m0, m1) & 0xFFFFFFFFu);
        }
        __syncthreads();   // nl/xsT/wred reused next batch
    }
}
#undef RSTEP

// Gather quantized, STE output, loss partials, histogram + coalesced dw scatter.
__global__ void __launch_bounds__(256)
assign_kernel(const float* __restrict__ x, const float* __restrict__ w,
              const int* __restrict__ best_idx,
              float* __restrict__ out, float* __restrict__ counts,
              float* __restrict__ dw, float* __restrict__ loss_acc) {
    __shared__ float xs[64][CDIM + 1];
    __shared__ int   sidx[64];
    __shared__ float red[256];

    int t  = threadIdx.x;
    int n0 = blockIdx.x * 64;
    int b  = n0 >> 12;
    int hw0 = n0 & (HWDIM - 1);
    const float* xbase = x + b * CHW + hw0;

    if (t < 64) {
        int idx = best_idx[n0 + t];
        sidx[t] = idx;
        out[O_IDX + n0 + t] = (float)idx;
        atomicAdd(&counts[idx], 1.0f);
    }

    int lane = t & 63, wv = t >> 6;
#pragma unroll
    for (int j = 0; j < 16; ++j) {
        int c = wv + j * 4;
        xs[lane][c] = xbase[c * HWDIM + lane];
    }
    __syncthreads();

    float lsum = 0.f;
#pragma unroll
    for (int j = 0; j < 16; ++j) {
        int c = wv + j * 4;
        float xv = xs[lane][c];
        float qv = w[sidx[lane] * CDIM + c];
        float d = qv - xv;
        out[O_Q + b * CHW + c * HWDIM + hw0 + lane] = xv + d;
        lsum = fmaf(d, d, lsum);
    }
    red[t] = lsum;
    __syncthreads();
    for (int s = 128; s > 0; s >>= 1) {
        if (t < s) red[t] += red[t + s];
        __syncthreads();
    }
    if (t == 0) atomicAdd(loss_acc, red[0]);

    for (int i = 0; i < 16; ++i) {
        int nl = wv * 16 + i;
        atomicAdd(&dw[sidx[nl] * CDIM + lane], xs[nl][lane]);  // wave-coalesced row
    }
}

// One fused elementwise pass over [4096,64]: new_cluster_size, new_ema_w,
// new_weight, loss. n = 0.99*sum(ecs) + 0.01*65536 (counts sum analytically).
__global__ void __launch_bounds__(256)
finalize_all(const float* __restrict__ ecs, const float* __restrict__ counts,
             const float* __restrict__ ema_w, const float* __restrict__ dw,
             const float* __restrict__ loss_acc, const float* __restrict__ esum,
             float* __restrict__ out) {
    int e = blockIdx.x * 256 + threadIdx.x;   // 0..262143
    int k = e >> 6;                            // wave-uniform
    float ncs = 0.99f * ecs[k] + 0.01f * counts[k];
    if ((e & 63) == 0) out[O_CS + k] = ncs;
    if (e == 0) out[O_LOSS] = 0.25f * loss_acc[0] / 4194304.0f;
    float n = 0.99f * esum[0] + 0.01f * 65536.0f;
    float cs = (ncs + 1e-5f) / (n + NUM_K * 1e-5f) * n;
    float ew = 0.99f * ema_w[e] + 0.01f * dw[e];
    out[O_EW + e] = ew;
    out[O_W + e] = ew / cs;
}

extern "C" void kernel_launch(void* const* d_in, const int* in_sizes, int n_in,
                              void* d_out, int out_size, void* d_ws, size_t ws_size,
                              hipStream_t stream) {
    const float* x     = (const float*)d_in[0];
    const float* w     = (const float*)d_in[1];
    const float* ecs   = (const float*)d_in[2];
    const float* ema_w = (const float*)d_in[3];
    float* out = (float*)d_out;
    float* ws  = (float*)d_ws;

    float* wsqh   = ws + W_WSQ;
    int*   bidx   = (int*)(ws + W_BIDX);
    float* counts = ws + W_CNT;
    float* loss_a = ws + W_LOSS;
    float* esum   = ws + W_ESUM;
    int*   rcnt   = (int*)(ws + W_RCNT);
    float* dw     = ws + W_DW;

    // scratch in the O_Q output region (overwritten by assign later):
    // wh/wl bf16 codebook [0,262144); rlist [262144,327680);
    // keys[4][65536] u64 [327680,851968); b2s[4][65536] [851968,1114112)
    __bf16* wh = (__bf16*)out;
    __bf16* wl = wh + NUM_K * CDIM;
    int* rlist = (int*)(out + 262144);
    u64* keys  = (u64*)(out + 327680);
    float* b2s = out + 851968;

    prep_kernel<<<NUM_K / 4, 256, 0, stream>>>(w, wsqh, wh, wl, counts, dw);
    argmin_mfma<<<dim3(NVEC / 128, 2), 128, 32768, stream>>>(x, wh, wl, wsqh, keys, b2s);
    combine_kernel<<<NVEC / 256, 256, 0, stream>>>(keys, b2s, ecs, esum, bidx, rcnt, rlist);
    rescue_kernel<<<256, 256, 0, stream>>>(x, w, wsqh, bidx, rcnt, rlist);
    assign_kernel<<<NVEC / 64, 256, 0, stream>>>(x, w, bidx, out, counts, dw, loss_a);
    finalize_all<<<CHW / 256, 256, 0, stream>>>(ecs, counts, ema_w, dw, loss_a, esum, out);
}